// Round 3
// baseline (241.653 us; speedup 1.0000x reference)
//
#include <hip/hip_runtime.h>

// SpectralConv3d (B=4, D=64^3, CIN=COUT=32, M=8^3):
//   fftn axes (2,3,4) = (D2, D3, CIN); D1 only sliced to <8 => out zero for d1>=8
//   Weff[c,o,k] = sum_ij w[c,o,i,j,k];  T[c][f3][co] folds DFT_c*mix*IDFT_c
//   norm 1/131072
// Pipeline: k_weff(32wg) -> k_T(32wg) -> k_fwd(256wg, x->S6 fused) -> k_out(4608wg)

#define PI2F 6.28318530717958647692f

// Weff[fc][o][f3] = sum_{ij} (wr + i wi)[fc][o][i][j][f3]
__global__ void k_weff(const float* __restrict__ wr, const float* __restrict__ wi,
                       float2* __restrict__ Weff) {
    int t = blockIdx.x * 256 + threadIdx.x;   // 8192
    int base = (t >> 3) * 512 + (t & 7);      // (fc*32+o)*512 + f3; ij stride 8
    float sr = 0.f, si = 0.f;
    #pragma unroll 8
    for (int ij = 0; ij < 64; ++ij) { sr += wr[base + ij * 8]; si += wi[base + ij * 8]; }
    Weff[t] = make_float2(sr, si);
}

// T[c][f3][co] = sum_{fc,o} E32^-(fc c) Weff[fc][o][f3] E32^+(o co)
__global__ void k_T(const float2* __restrict__ Weff, float2* __restrict__ T) {
    __shared__ float2 tw32[32];
    __shared__ float2 A[256];
    int t = threadIdx.x;
    int c = blockIdx.x;
    if (t < 32) {
        float s, co_;
        __sincosf((PI2F / 32.f) * (float)t, &s, &co_);
        tw32[t] = make_float2(co_, s);
    }
    __syncthreads();
    {   // A[o][f3] = sum_fc Weff[fc][o][f3] * E^-(fc*c)
        float2 acc = make_float2(0.f, 0.f);
        for (int fc = 0; fc < 32; ++fc) {
            float2 v = Weff[fc * 256 + t];
            float2 e = tw32[(fc * c) & 31];
            acc.x += v.x * e.x + v.y * e.y;
            acc.y += v.y * e.x - v.x * e.y;
        }
        A[t] = acc;
    }
    __syncthreads();
    {   // T[c][f3][co] = sum_o A[o][f3] * E^+(o*co)
        int f3 = t >> 5, co = t & 31;
        float2 acc = make_float2(0.f, 0.f);
        for (int o = 0; o < 32; ++o) {
            float2 v = A[o * 8 + f3];
            float2 e = tw32[(o * co) & 31];
            acc.x += v.x * e.x - v.y * e.y;
            acc.y += v.x * e.y + v.y * e.x;
        }
        T[c * 256 + t] = acc;
    }
}

// Fused forward: block per (f2, b, d1); gid = f2*32 + (b*8+d1) so the 8
// f2-siblings sharing an x-slab land on the same XCD (stride 32 ≡ 0 mod 8).
//   phase A: lin[d3][c]  = DFT_d2 of x slab (direct from global, tw table)
//   phase B: ls2[f3][c]  = DFT_d3
//   phase C: ls5[f3][co] = sum_c ls2 * T[c][f3][co]
//   phase D: S6[d3][co]  = IDFT_f3
__global__ void k_fwd(const float* __restrict__ x, const float2* __restrict__ T,
                      float2* __restrict__ S6) {
    __shared__ float2 lin[2048];    // [d3][c] 16 KiB
    __shared__ float2 ls2[256];     // [f3][c]
    __shared__ float2 ls5[256];     // [f3][co]
    __shared__ float2 tw64[64];
    int t = threadIdx.x;
    int gid = blockIdx.x;
    int f2 = gid >> 5;
    int bd1 = gid & 31;
    if (t < 64) {
        float s, c;
        __sincosf((PI2F / 64.f) * (float)t, &s, &c);
        tw64[t] = make_float2(c, s);
    }
    __syncthreads();
    // phase A: 2 tasks/thread; task -> (d3 = task>>3, c4 = task&7)
    {
        int b = bd1 >> 3, d1 = bd1 & 7;
        const float4* xp = (const float4*)(x + (size_t)b * 8388608 + (size_t)d1 * 131072);
        int d3a = t >> 3,        c4a = t & 7;
        int d3b = (t + 256) >> 3, c4b = t & 7;   // task1 = t+256: low 3 bits same
        const float4* xa = xp + d3a * 8 + c4a;
        const float4* xb = xp + d3b * 8 + c4b;
        float2 A0{0,0}, A1{0,0}, A2{0,0}, A3{0,0};
        float2 B0{0,0}, B1{0,0}, B2{0,0}, B3{0,0};
        #pragma unroll 4
        for (int d2 = 0; d2 < 64; ++d2) {
            float2 e = tw64[(f2 * d2) & 63];     // use conj for forward
            float4 va = xa[d2 * 512];
            float4 vb = xb[d2 * 512];
            A0.x += va.x * e.x; A0.y -= va.x * e.y;
            A1.x += va.y * e.x; A1.y -= va.y * e.y;
            A2.x += va.z * e.x; A2.y -= va.z * e.y;
            A3.x += va.w * e.x; A3.y -= va.w * e.y;
            B0.x += vb.x * e.x; B0.y -= vb.x * e.y;
            B1.x += vb.y * e.x; B1.y -= vb.y * e.y;
            B2.x += vb.z * e.x; B2.y -= vb.z * e.y;
            B3.x += vb.w * e.x; B3.y -= vb.w * e.y;
        }
        float4* lp = (float4*)lin;
        lp[d3a * 16 + c4a * 2]     = make_float4(A0.x, A0.y, A1.x, A1.y);
        lp[d3a * 16 + c4a * 2 + 1] = make_float4(A2.x, A2.y, A3.x, A3.y);
        lp[d3b * 16 + c4b * 2]     = make_float4(B0.x, B0.y, B1.x, B1.y);
        lp[d3b * 16 + c4b * 2 + 1] = make_float4(B2.x, B2.y, B3.x, B3.y);
    }
    __syncthreads();
    // phase B: t -> (f3 = t>>5, c = t&31)
    {
        int f3 = t >> 5, c = t & 31;
        float2 acc = make_float2(0.f, 0.f);
        for (int d3 = 0; d3 < 64; ++d3) {
            float2 v = lin[d3 * 32 + c];
            float2 e = tw64[(f3 * d3) & 63];
            acc.x += v.x * e.x + v.y * e.y;
            acc.y += v.y * e.x - v.x * e.y;
        }
        ls2[t] = acc;
    }
    __syncthreads();
    // phase C: t -> (f3, co); T layout [c][f3*32+co]
    {
        int f3 = t >> 5;
        float2 acc = make_float2(0.f, 0.f);
        for (int c = 0; c < 32; ++c) {
            float2 a = ls2[f3 * 32 + c];
            float2 w = T[c * 256 + t];
            acc.x += a.x * w.x - a.y * w.y;
            acc.y += a.x * w.y + a.y * w.x;
        }
        ls5[t] = acc;
    }
    __syncthreads();
    // phase D: t -> (co = t&31, d3r = t>>5); S6 slab (bd1*8+f2)
    {
        int co = t & 31, d3r = t >> 5;
        float2* outp = S6 + (size_t)(bd1 * 8 + f2) * 2048;
        #pragma unroll
        for (int j = 0; j < 8; ++j) {
            int d3 = d3r + 8 * j;
            float2 acc = make_float2(0.f, 0.f);
            #pragma unroll
            for (int f3 = 0; f3 < 8; ++f3) {
                float2 v = ls5[f3 * 32 + co];
                float2 e = tw64[(f3 * d3) & 63];
                acc.x += v.x * e.x - v.y * e.y;
                acc.y += v.x * e.y + v.y * e.x;
            }
            outp[d3 * 32 + co] = acc;
        }
    }
}

// Output: grid (1152, 4). y = b. x<256: compute (d2g = x>>5, d1 = (x>>2)&7,
// d3q = x&3) — d2g-siblings (stride 32) share XCD, slab loaded once to LDS,
// re-used across 8 d2. x>=256: pure zero-store for d1>=8.
__global__ void k_out(const float2* __restrict__ S6, float* __restrict__ out) {
    __shared__ float2 slab[8][16][32];   // [f2][d3l][co] 32 KiB
    __shared__ float2 tw64[64];
    int t = threadIdx.x;
    int b = blockIdx.y;
    int xb = blockIdx.x;
    if (xb >= 256) {
        // zero region: d1 in [8,64): 28 MiB per b = 1835008 float4
        int z = xb - 256;
        float4* op = (float4*)out + (size_t)b * 2097152 + 262144 + (size_t)z * 2048;
        float4 zero = make_float4(0.f, 0.f, 0.f, 0.f);
        #pragma unroll
        for (int i = 0; i < 8; ++i) op[i * 256 + t] = zero;
        return;
    }
    int d2g = xb >> 5, d1 = (xb >> 2) & 7, d3q = xb & 3;
    int bd1 = b * 8 + d1;
    if (t < 64) {
        float s, c;
        __sincosf((PI2F / 64.f) * (float)t, &s, &c);
        tw64[t] = make_float2(c, s);
    }
    // load slab: 2048 float4, coalesced
    {
        const float4* src = (const float4*)S6 + (size_t)bd1 * 8192 + d3q * 256;
        float4* dst = (float4*)slab;
        #pragma unroll
        for (int i = 0; i < 8; ++i) {
            int f4l = t + 256 * i;
            int f2 = f4l >> 8, rem = f4l & 255;
            dst[f4l] = src[f2 * 1024 + rem];
        }
    }
    __syncthreads();
    // thread -> (co4 = t&7, d2l = (t>>3)&7, d3r = t>>6)
    int co4 = t & 7, d2l = (t >> 3) & 7, d3r = t >> 6;
    int d2 = d2g * 8 + d2l;
    float twr[8], twi[8];
    #pragma unroll
    for (int f2 = 0; f2 < 8; ++f2) {
        float2 e = tw64[(f2 * d2) & 63];
        twr[f2] = e.x; twi[f2] = e.y;
    }
    const float sc = 1.f / 131072.f;
    float4* op = (float4*)out + ((size_t)(b * 64 + d1) * 64 + d2) * 512;
    #pragma unroll
    for (int k = 0; k < 4; ++k) {
        int d3l = d3r * 4 + k;           // 0..15
        int d3 = d3q * 16 + d3l;
        float a0 = 0.f, a1 = 0.f, a2 = 0.f, a3 = 0.f;
        #pragma unroll
        for (int f2 = 0; f2 < 8; ++f2) {
            const float4* sp = (const float4*)&slab[f2][d3l][co4 * 4];
            float4 v01 = sp[0];
            float4 v23 = sp[1];
            a0 += v01.x * twr[f2] - v01.y * twi[f2];
            a1 += v01.z * twr[f2] - v01.w * twi[f2];
            a2 += v23.x * twr[f2] - v23.y * twi[f2];
            a3 += v23.z * twr[f2] - v23.w * twi[f2];
        }
        op[d3 * 8 + co4] = make_float4(a0 * sc, a1 * sc, a2 * sc, a3 * sc);
    }
}

extern "C" void kernel_launch(void* const* d_in, const int* in_sizes, int n_in,
                              void* d_out, int out_size, void* d_ws, size_t ws_size,
                              hipStream_t stream) {
    const float* x  = (const float*)d_in[0];
    const float* wr = (const float*)d_in[1];
    const float* wi = (const float*)d_in[2];
    float* out = (float*)d_out;

    float2* Weff = (float2*)d_ws;            // 8192
    float2* T    = Weff + 8192;              // 8192
    float2* S6   = T + 8192;                 // 524288 (4 MiB)

    k_weff<<<32,  256, 0, stream>>>(wr, wi, Weff);
    k_T   <<<32,  256, 0, stream>>>(Weff, T);
    k_fwd <<<256, 256, 0, stream>>>(x, T, S6);
    k_out <<<dim3(1152, 4), 256, 0, stream>>>(S6, out);
}